// Round 1
// baseline (161.849 us; speedup 1.0000x reference)
//
#include <hip/hip_runtime.h>

#define NPTS 131072
#define G0 512
#define G1 512
#define G2 128

typedef float v4f __attribute__((ext_vector_type(4)));
typedef __attribute__((ext_vector_type(8))) short short8;

// persistent device scratch (rewritten every launch; no hipMalloc in capture)
__device__ float g_linesT[4*(G0+G1+G2)*32];        // [axis][k][g][r]
__device__ unsigned short g_featB[3*4*2*64*8];     // [plane][s][tcol][lane][j] bf16 bits

__device__ __forceinline__ unsigned short bf16rne(float x){
  unsigned int u = __float_as_uint(x);
  u += 0x7fffu + ((u >> 16) & 1u);
  return (unsigned short)(u >> 16);
}

__global__ void prep_lines(const float* __restrict__ c0,
                           const float* __restrict__ c1,
                           const float* __restrict__ c2,
                           const int* __restrict__ topk_id) {
  int e = blockIdx.x*blockDim.x + threadIdx.x;
  const int T0 = 4*G0*32, T1 = 4*G1*32, T2 = 4*G2*32;
  if (e >= T0+T1+T2) return;
  const float* src; int G; int e2 = e;
  if (e2 < T0)            { src = c0; G = G0; }
  else if (e2 < T0+T1)    { e2 -= T0; src = c1; G = G1; }
  else                    { e2 -= T0+T1; src = c2; G = G2; }
  int kk  = e2 / (G*32);
  int rem = e2 - kk*G*32;
  int g = rem >> 5;
  int r = rem & 31;
  int id = topk_id[kk];
  g_linesT[e] = src[(id*32 + r)*G + g];
}

__global__ void prep_featB(const float* __restrict__ f0,
                           const float* __restrict__ f1,
                           const float* __restrict__ f2,
                           const float* __restrict__ tw,
                           const int* __restrict__ topk_id) {
  int e = blockIdx.x*blockDim.x + threadIdx.x;
  if (e >= 3*4*2*64*8) return;
  int j    =  e        & 7;
  int lane = (e >> 3)  & 63;
  int tcol = (e >> 9)  & 1;
  int s    = (e >> 10) & 3;
  int p    =  e >> 12;
  int r = ((lane >> 4) << 3) + j;       // B-operand k index = r
  int c = tcol*16 + (lane & 15);        // B-operand n index = c
  const float* f = (p == 0) ? f0 : ((p == 1) ? f1 : f2);
  float v = tw[s] * f[(topk_id[s]*32 + r)*32 + c];
  g_featB[e] = bf16rne(v);
}

__global__ __launch_bounds__(256) void fuse_main(
    const float* __restrict__ pts, const float* __restrict__ dirs,
    const float* __restrict__ sw,  const float* __restrict__ Am,
    const float* __restrict__ Bm,  const float* __restrict__ tb,
    float* __restrict__ out)
{
  __shared__ float sA[384];
  __shared__ float sB[384];
  __shared__ unsigned short sFeat[3*4*2*64*8];
  __shared__ int   sI0[3][256];
  __shared__ int   sI1[3][256];
  __shared__ float sWw[3][256];

  const int tid = threadIdx.x;

  // cooperative staging
  for (int i = tid; i < 384; i += 256){ sA[i] = Am[i]; sB[i] = Bm[i]; }
  {
    const uint4* gs = reinterpret_cast<const uint4*>(g_featB);
    uint4* gd = reinterpret_cast<uint4*>(sFeat);
    for (int i = tid; i < (3*4*2*64*8)/8; i += 256) gd[i] = gs[i];
  }
  __syncthreads();

  // ---------------- phase 1: per-point skinning + transforms ----------------
  const int n = blockIdx.x*256 + tid;
  float swv[24];
  {
    const float4* swp = reinterpret_cast<const float4*>(sw + n*24);
    #pragma unroll
    for (int i = 0; i < 6; i++){
      float4 v = swp[i];
      swv[4*i] = v.x; swv[4*i+1] = v.y; swv[4*i+2] = v.z; swv[4*i+3] = v.w;
    }
  }
  float RA[9] = {0,0,0,0,0,0,0,0,0}, tA[3] = {0,0,0};
  float RB[9] = {0,0,0,0,0,0,0,0,0}, tB[3] = {0,0,0};
  #pragma unroll
  for (int j = 0; j < 24; j++){
    float w = swv[j];
    const float* a = sA + j*16;
    const float* b = sB + j*16;
    RA[0] = fmaf(w, a[0], RA[0]); RA[1] = fmaf(w, a[1], RA[1]); RA[2] = fmaf(w, a[2], RA[2]); tA[0] = fmaf(w, a[3],  tA[0]);
    RA[3] = fmaf(w, a[4], RA[3]); RA[4] = fmaf(w, a[5], RA[4]); RA[5] = fmaf(w, a[6], RA[5]); tA[1] = fmaf(w, a[7],  tA[1]);
    RA[6] = fmaf(w, a[8], RA[6]); RA[7] = fmaf(w, a[9], RA[7]); RA[8] = fmaf(w, a[10],RA[8]); tA[2] = fmaf(w, a[11], tA[2]);
    RB[0] = fmaf(w, b[0], RB[0]); RB[1] = fmaf(w, b[1], RB[1]); RB[2] = fmaf(w, b[2], RB[2]); tB[0] = fmaf(w, b[3],  tB[0]);
    RB[3] = fmaf(w, b[4], RB[3]); RB[4] = fmaf(w, b[5], RB[4]); RB[5] = fmaf(w, b[6], RB[5]); tB[1] = fmaf(w, b[7],  tB[1]);
    RB[6] = fmaf(w, b[8], RB[6]); RB[7] = fmaf(w, b[9], RB[7]); RB[8] = fmaf(w, b[10],RB[8]); tB[2] = fmaf(w, b[11], tB[2]);
  }
  // 3x3 inverse of RA via adjugate
  float c00 = RA[4]*RA[8] - RA[5]*RA[7];
  float c01 = RA[5]*RA[6] - RA[3]*RA[8];
  float c02 = RA[3]*RA[7] - RA[4]*RA[6];
  float det = RA[0]*c00 + RA[1]*c01 + RA[2]*c02;
  float idet = 1.0f/det;
  float i00 = c00*idet;
  float i01 = (RA[2]*RA[7] - RA[1]*RA[8])*idet;
  float i02 = (RA[1]*RA[5] - RA[2]*RA[4])*idet;
  float i10 = c01*idet;
  float i11 = (RA[0]*RA[8] - RA[2]*RA[6])*idet;
  float i12 = (RA[2]*RA[3] - RA[0]*RA[5])*idet;
  float i20 = c02*idet;
  float i21 = (RA[1]*RA[6] - RA[0]*RA[7])*idet;
  float i22 = (RA[0]*RA[4] - RA[1]*RA[3])*idet;

  float px = pts[n*3+0], py = pts[n*3+1], pz = pts[n*3+2];
  float dx = dirs[n*3+0], dy = dirs[n*3+1], dz = dirs[n*3+2];
  float qx = px - tA[0], qy = py - tA[1], qz = pz - tA[2];
  float tpx = i00*qx + i01*qy + i02*qz;
  float tpy = i10*qx + i11*qy + i12*qz;
  float tpz = i20*qx + i21*qy + i22*qz;
  float cx = RB[0]*tpx + RB[1]*tpy + RB[2]*tpz + tB[0];
  float cy = RB[3]*tpx + RB[4]*tpy + RB[5]*tpz + tB[1];
  float cz = RB[6]*tpx + RB[7]*tpy + RB[8]*tpz + tB[2];
  float tdx = i00*dx + i01*dy + i02*dz;
  float tdy = i10*dx + i11*dy + i12*dz;
  float tdz = i20*dx + i21*dy + i22*dz;
  float cdx = RB[0]*tdx + RB[1]*tdy + RB[2]*tdz;
  float cdy = RB[3]*tdx + RB[4]*tdy + RB[5]*tdz;
  float cdz = RB[6]*tdx + RB[7]*tdy + RB[8]*tdz;

  {
    float* o = out + (size_t)n*102;
    o[0] = cx; o[1] = cy; o[2] = cz; o[3] = cdx; o[4] = cdy; o[5] = cdz;
  }

  // normalized coords -> (i0,i1,w) per axis
  {
    float lo0 = tb[0], lo1 = tb[1], lo2 = tb[2];
    float hi0 = tb[3], hi1 = tb[4], hi2 = tb[5];
    float xs[3]; int Gs[3] = {G0, G1, G2};
    xs[0] = (cx - lo0)/(hi0 - lo0)*2.0f - 1.0f;
    xs[1] = (cy - lo1)/(hi1 - lo1)*2.0f - 1.0f;
    xs[2] = (cz - lo2)/(hi2 - lo2)*2.0f - 1.0f;
    #pragma unroll
    for (int a = 0; a < 3; a++){
      float pos = (xs[a] + 1.0f)*0.5f*(float)(Gs[a]-1);
      float fi = floorf(pos);
      fi = fminf(fmaxf(fi, 0.0f), (float)(Gs[a]-1));
      int i0 = (int)fi;
      int i1 = min(i0 + 1, Gs[a]-1);
      float w = pos - (float)i0;
      sI0[a][tid] = i0; sI1[a][tid] = i1; sWw[a][tid] = w;
    }
  }
  __syncthreads();

  // ---------------- phase 2: MFMA einsum, 16 points per wave-tile ----------------
  const int lane = tid & 63;
  const int wv   = tid >> 6;
  const int m    = lane & 15;
  const int q    = lane >> 4;
  const float* lt0 = g_linesT;
  const float* lt1 = g_linesT + 4*G0*32;
  const float* lt2 = g_linesT + 4*(G0+G1)*32;
  const short8* fb = reinterpret_cast<const short8*>(sFeat);

  for (int t = 0; t < 4; t++){
    const int pl = wv*64 + t*16 + m;
    const int a0i0 = sI0[0][pl], a0i1 = sI1[0][pl];
    const int a1i0 = sI0[1][pl], a1i1 = sI1[1][pl];
    const int a2i0 = sI0[2][pl], a2i1 = sI1[2][pl];
    const float w0 = sWw[0][pl], w1 = sWw[1][pl], w2 = sWw[2][pl];
    v4f acc00 = {0,0,0,0}, acc01 = {0,0,0,0};
    v4f acc10 = {0,0,0,0}, acc11 = {0,0,0,0};
    v4f acc20 = {0,0,0,0}, acc21 = {0,0,0,0};
    #pragma unroll
    for (int s = 0; s < 4; s++){
      float c0[8], c1[8], c2[8];
      {
        const float* p0 = lt0 + (s*G0 + a0i0)*32 + q*8;
        const float* p1 = lt0 + (s*G0 + a0i1)*32 + q*8;
        float4 v0a = *(const float4*)p0, v0b = *(const float4*)(p0+4);
        float4 v1a = *(const float4*)p1, v1b = *(const float4*)(p1+4);
        c0[0] = fmaf(w0, v1a.x - v0a.x, v0a.x);
        c0[1] = fmaf(w0, v1a.y - v0a.y, v0a.y);
        c0[2] = fmaf(w0, v1a.z - v0a.z, v0a.z);
        c0[3] = fmaf(w0, v1a.w - v0a.w, v0a.w);
        c0[4] = fmaf(w0, v1b.x - v0b.x, v0b.x);
        c0[5] = fmaf(w0, v1b.y - v0b.y, v0b.y);
        c0[6] = fmaf(w0, v1b.z - v0b.z, v0b.z);
        c0[7] = fmaf(w0, v1b.w - v0b.w, v0b.w);
      }
      {
        const float* p0 = lt1 + (s*G1 + a1i0)*32 + q*8;
        const float* p1 = lt1 + (s*G1 + a1i1)*32 + q*8;
        float4 v0a = *(const float4*)p0, v0b = *(const float4*)(p0+4);
        float4 v1a = *(const float4*)p1, v1b = *(const float4*)(p1+4);
        c1[0] = fmaf(w1, v1a.x - v0a.x, v0a.x);
        c1[1] = fmaf(w1, v1a.y - v0a.y, v0a.y);
        c1[2] = fmaf(w1, v1a.z - v0a.z, v0a.z);
        c1[3] = fmaf(w1, v1a.w - v0a.w, v0a.w);
        c1[4] = fmaf(w1, v1b.x - v0b.x, v0b.x);
        c1[5] = fmaf(w1, v1b.y - v0b.y, v0b.y);
        c1[6] = fmaf(w1, v1b.z - v0b.z, v0b.z);
        c1[7] = fmaf(w1, v1b.w - v0b.w, v0b.w);
      }
      {
        const float* p0 = lt2 + (s*G2 + a2i0)*32 + q*8;
        const float* p1 = lt2 + (s*G2 + a2i1)*32 + q*8;
        float4 v0a = *(const float4*)p0, v0b = *(const float4*)(p0+4);
        float4 v1a = *(const float4*)p1, v1b = *(const float4*)(p1+4);
        c2[0] = fmaf(w2, v1a.x - v0a.x, v0a.x);
        c2[1] = fmaf(w2, v1a.y - v0a.y, v0a.y);
        c2[2] = fmaf(w2, v1a.z - v0a.z, v0a.z);
        c2[3] = fmaf(w2, v1a.w - v0a.w, v0a.w);
        c2[4] = fmaf(w2, v1b.x - v0b.x, v0b.x);
        c2[5] = fmaf(w2, v1b.y - v0b.y, v0b.y);
        c2[6] = fmaf(w2, v1b.z - v0b.z, v0b.z);
        c2[7] = fmaf(w2, v1b.w - v0b.w, v0b.w);
      }
      short8 A0, A1, A2;
      #pragma unroll
      for (int j = 0; j < 8; j++){
        A0[j] = (short)bf16rne(c0[j]*c1[j]);
        A1[j] = (short)bf16rne(c0[j]*c2[j]);
        A2[j] = (short)bf16rne(c1[j]*c2[j]);
      }
      short8 B00 = fb[(0*8 + s*2 + 0)*64 + lane];
      short8 B01 = fb[(0*8 + s*2 + 1)*64 + lane];
      short8 B10 = fb[(1*8 + s*2 + 0)*64 + lane];
      short8 B11 = fb[(1*8 + s*2 + 1)*64 + lane];
      short8 B20 = fb[(2*8 + s*2 + 0)*64 + lane];
      short8 B21 = fb[(2*8 + s*2 + 1)*64 + lane];
      acc00 = __builtin_amdgcn_mfma_f32_16x16x32_bf16(A0, B00, acc00, 0, 0, 0);
      acc01 = __builtin_amdgcn_mfma_f32_16x16x32_bf16(A0, B01, acc01, 0, 0, 0);
      acc10 = __builtin_amdgcn_mfma_f32_16x16x32_bf16(A1, B10, acc10, 0, 0, 0);
      acc11 = __builtin_amdgcn_mfma_f32_16x16x32_bf16(A1, B11, acc11, 0, 0, 0);
      acc20 = __builtin_amdgcn_mfma_f32_16x16x32_bf16(A2, B20, acc20, 0, 0, 0);
      acc21 = __builtin_amdgcn_mfma_f32_16x16x32_bf16(A2, B21, acc21, 0, 0, 0);
    }
    const int rowBase = blockIdx.x*256 + wv*64 + t*16 + q*4;
    #pragma unroll
    for (int v = 0; v < 4; v++){
      float* o = out + (size_t)(rowBase + v)*102 + 6 + m;
      o[0]  = acc00[v];
      o[16] = acc01[v];
      o[32] = acc10[v];
      o[48] = acc11[v];
      o[64] = acc20[v];
      o[80] = acc21[v];
    }
  }
}

extern "C" void kernel_launch(void* const* d_in, const int* in_sizes, int n_in,
                              void* d_out, int out_size, void* d_ws, size_t ws_size,
                              hipStream_t stream) {
  const float* pose_pts  = (const float*)d_in[0];
  const float* pose_dirs = (const float*)d_in[1];
  const float* sw        = (const float*)d_in[2];
  const float* Am        = (const float*)d_in[3];
  const float* Bm        = (const float*)d_in[4];
  const float* tb        = (const float*)d_in[5];
  const float* cl0       = (const float*)d_in[6];
  const float* cl1       = (const float*)d_in[7];
  const float* cl2       = (const float*)d_in[8];
  const float* fl0       = (const float*)d_in[9];
  const float* fl1       = (const float*)d_in[10];
  const float* fl2       = (const float*)d_in[11];
  const float* tw        = (const float*)d_in[12];
  const int*   tkid      = (const int*)d_in[13];
  float* out = (float*)d_out;

  hipLaunchKernelGGL(prep_lines, dim3((4*(G0+G1+G2)*32 + 255)/256), dim3(256), 0, stream,
                     cl0, cl1, cl2, tkid);
  hipLaunchKernelGGL(prep_featB, dim3((3*4*2*64*8 + 255)/256), dim3(256), 0, stream,
                     fl0, fl1, fl2, tw, tkid);
  hipLaunchKernelGGL(fuse_main, dim3(NPTS/256), dim3(256), 0, stream,
                     pose_pts, pose_dirs, sw, Am, Bm, tb, out);
}